// Round 5
// baseline (211.603 us; speedup 1.0000x reference)
//
#include <hip/hip_runtime.h>
#include <hip/hip_bf16.h>
#include <math.h>

// Problem constants
#define NB    8          // batch
#define CIN   512        // in channels
#define HW    3136       // 56*56
#define CH    128        // attention channels
#define TCH   384        // 3*CH
#define SCALE 0.08838834764831845f   // 128^-0.5
#define BNEPS 1e-5f
#define NSPLIT 3         // KV splits for attention

typedef __attribute__((ext_vector_type(8))) short bf16x8;   // 8 bf16 (4 VGPRs)
typedef __attribute__((ext_vector_type(4))) short bf16x4;   // 4 bf16 (2 VGPRs)
typedef __attribute__((ext_vector_type(4))) float f32x4;    // MFMA accumulator

#define MFMA16(a, b, c) __builtin_amdgcn_mfma_f32_16x16x32_bf16((a), (b), (c), 0, 0, 0)

__device__ inline short f2bf(float f) {
    __hip_bfloat16 h = __float2bfloat16(f);
    return *reinterpret_cast<short*>(&h);
}
__device__ inline unsigned pack2bf(float a, float b) {
    return (unsigned)(unsigned short)f2bf(a) | ((unsigned)(unsigned short)f2bf(b) << 16);
}
__device__ inline float bfraw2f(unsigned short u) {
    return __uint_as_float(((unsigned)u) << 16);
}

// ---------------------------------------------------------------------------
// Kernel 0a: convert Ww (384x512) and Zw (512x128) f32 -> bf16, row-major.
// ---------------------------------------------------------------------------
__global__ __launch_bounds__(256) void cvt_wts(const float* __restrict__ Ww,
                                               const float* __restrict__ Zw,
                                               __hip_bfloat16* __restrict__ WwB,
                                               __hip_bfloat16* __restrict__ ZwB) {
    const int nW = TCH * CIN / 4;   // 49152 float4 chunks
    const int nZ = CIN * CH / 4;    // 16384
    int i = blockIdx.x * 256 + threadIdx.x;
    if (i < nW) {
        float4 v = ((const float4*)Ww)[i];
        bf16x4 o; o[0] = f2bf(v.x); o[1] = f2bf(v.y); o[2] = f2bf(v.z); o[3] = f2bf(v.w);
        ((bf16x4*)WwB)[i] = o;
    } else if (i < nW + nZ) {
        int j = i - nW;
        float4 v = ((const float4*)Zw)[j];
        bf16x4 o; o[0] = f2bf(v.x); o[1] = f2bf(v.y); o[2] = f2bf(v.z); o[3] = f2bf(v.w);
        ((bf16x4*)ZwB)[j] = o;
    }
}

// ---------------------------------------------------------------------------
// Kernel 0b: xT[n][q][c] bf16 = transpose+cvt of x[n][c][q] f32.
// ---------------------------------------------------------------------------
__global__ __launch_bounds__(256) void xpose_kernel(const float* __restrict__ x,
                                                    __hip_bfloat16* __restrict__ xT) {
    const int n = blockIdx.z, c0 = blockIdx.y * 64, q0 = blockIdx.x * 64;
    const int tid = threadIdx.x;
    const int mr = tid >> 4, mq = tid & 15;

    __shared__ char T[64 * 128];   // [q][64 c] bf16, byte ^= ((q&15)<<3)

    const float* xp = x + ((size_t)(n * CIN + c0 + mr * 4)) * HW + q0 + mq * 4;
    float4 r0 = *(const float4*)(xp);
    float4 r1 = *(const float4*)(xp + HW);
    float4 r2 = *(const float4*)(xp + 2 * HW);
    float4 r3 = *(const float4*)(xp + 3 * HW);
    const float* f0 = (const float*)&r0; const float* f1 = (const float*)&r1;
    const float* f2 = (const float*)&r2; const float* f3 = (const float*)&r3;
#pragma unroll
    for (int j = 0; j < 4; ++j) {
        int q = mq * 4 + j;
        bf16x4 v; v[0] = f2bf(f0[j]); v[1] = f2bf(f1[j]);
                  v[2] = f2bf(f2[j]); v[3] = f2bf(f3[j]);
        *(bf16x4*)(T + q * 128 + ((mr * 8) ^ ((q & 15) << 3))) = v;
    }
    __syncthreads();

    __hip_bfloat16* og = xT + ((size_t)n * HW + q0) * CIN + c0;
#pragma unroll
    for (int it = 0; it < 2; ++it) {
        int ch = it * 256 + tid, rr = ch >> 3, o8 = ch & 7;
        int sw = (rr & 15) << 3;
        bf16x4 lo = *(const bf16x4*)(T + rr * 128 + ((o8 * 16) ^ sw));
        bf16x4 hi = *(const bf16x4*)(T + rr * 128 + ((o8 * 16 + 8) ^ sw));
        bf16x8 v; v[0] = lo[0]; v[1] = lo[1]; v[2] = lo[2]; v[3] = lo[3];
                  v[4] = hi[0]; v[5] = hi[1]; v[6] = hi[2]; v[7] = hi[3];
        *(bf16x8*)(og + (size_t)rr * CIN + o8 * 8) = v;
    }
}

// ---------------------------------------------------------------------------
// Kernel 1: proj via MFMA (unchanged from R4).
// ---------------------------------------------------------------------------
__global__ __launch_bounds__(256) void proj_kernel(const __hip_bfloat16* __restrict__ xT,
                                                   const __hip_bfloat16* __restrict__ WwB,
                                                   const float* __restrict__ Wb,
                                                   __hip_bfloat16* __restrict__ Qt,
                                                   __hip_bfloat16* __restrict__ Kt,
                                                   __hip_bfloat16* __restrict__ Vg) {
    const int n  = blockIdx.z;
    const int m0 = blockIdx.y * 64;   // over 384
    const int q0 = blockIdx.x * 64;   // over 3136
    const int tid = threadIdx.x;
    const int lane = tid & 63, wv = tid >> 6;
    const int lr = lane & 15, hi = lane >> 4;

    __shared__ char Aw[64 * 128];  // [m][64 c] bf16, byte ^= ((r&7)<<4)
    __shared__ char Bx[64 * 128];  // [q][64 c]
    __shared__ char Ts[64 * 128];  // epilogue staging

    f32x4 acc[4] = {};
    const __hip_bfloat16* xn = xT + ((size_t)n * HW + q0) * CIN;

    for (int k0 = 0; k0 < CIN; k0 += 64) {
#pragma unroll
        for (int it = 0; it < 2; ++it) {
            int ch = it * 256 + tid, r = ch >> 3, o = ch & 7;
            int sw = (o * 16) ^ ((r & 7) << 4);
            bf16x8 a = *(const bf16x8*)(WwB + (size_t)(m0 + r) * CIN + k0 + o * 8);
            *(bf16x8*)(Aw + r * 128 + sw) = a;
            bf16x8 b = *(const bf16x8*)(xn + (size_t)r * CIN + k0 + o * 8);
            *(bf16x8*)(Bx + r * 128 + sw) = b;
        }
        __syncthreads();

        const int mrow = wv * 16 + lr;
#pragma unroll
        for (int ks = 0; ks < 2; ++ks) {
            bf16x8 af = *(const bf16x8*)(Aw + mrow * 128 +
                                         ((ks * 64 + hi * 16) ^ ((mrow & 7) << 4)));
#pragma unroll
            for (int kn = 0; kn < 4; ++kn) {
                int qrow = kn * 16 + lr;
                bf16x8 bfr = *(const bf16x8*)(Bx + qrow * 128 +
                                              ((ks * 64 + hi * 16) ^ ((qrow & 7) << 4)));
                acc[kn] = MFMA16(af, bfr, acc[kn]);
            }
        }
        __syncthreads();
    }

    const int region = m0 >> 7;     // 0=Q, 1=K, 2=V
    const int c0     = m0 & 127;    // 0 or 64

    float bias[4];
#pragma unroll
    for (int reg = 0; reg < 4; ++reg) bias[reg] = Wb[m0 + wv * 16 + hi * 4 + reg];

#pragma unroll
    for (int kn = 0; kn < 4; ++kn)
#pragma unroll
        for (int reg = 0; reg < 4; ++reg) {
            __hip_bfloat16 v = __float2bfloat16(acc[kn][reg] + bias[reg]);
            int row, colb;
            if (region < 2) { row = kn * 16 + lr; colb = (wv * 16 + hi * 4 + reg) * 2; }
            else            { row = wv * 16 + hi * 4 + reg; colb = (kn * 16 + lr) * 2; }
            *(__hip_bfloat16*)(Ts + row * 128 + (colb ^ ((row & 7) << 4))) = v;
        }
    __syncthreads();

    __hip_bfloat16* base;
    size_t rstride;
    if (region == 0)      { base = Qt + (size_t)n * HW * CH + (size_t)q0 * CH + c0; rstride = CH; }
    else if (region == 1) { base = Kt + (size_t)n * HW * CH + (size_t)q0 * CH + c0; rstride = CH; }
    else                  { base = Vg + (size_t)n * CH * HW + (size_t)c0 * HW + q0; rstride = HW; }

#pragma unroll
    for (int it = 0; it < 2; ++it) {
        int ch = it * 256 + tid, rr = ch >> 3, o = ch & 7;
        bf16x8 v = *(const bf16x8*)(Ts + rr * 128 + ((o * 16) ^ ((rr & 7) << 4)));
        *(bf16x8*)(base + (size_t)rr * rstride + o * 8) = v;
    }
}

// ---------------------------------------------------------------------------
// Kernel 2: flash attention, Nq=32/wave (2 q-subtiles), QBLK=112, KV-split 3.
// Writes unnormalized bf16 partial O~ + f32 m,l per (split, q).
// ---------------------------------------------------------------------------
__global__ __launch_bounds__(256) void attn_kernel(
        const __hip_bfloat16* __restrict__ Qt,   // [NB][HW][CH]
        const __hip_bfloat16* __restrict__ Kt,   // [NB][HW][CH]
        const __hip_bfloat16* __restrict__ Vg,   // [NB][CH][HW]
        __hip_bfloat16* __restrict__ PO,         // [NSPLIT][NB][HW][CH]
        float* __restrict__ Mbuf,                // [NSPLIT][NB][HW]
        float* __restrict__ Lbuf) {              // [NSPLIT][NB][HW]
    const int n = blockIdx.y, s = blockIdx.z;
    const int q0 = blockIdx.x * 112;
    const int tid = threadIdx.x, lane = tid & 63, wv = tid >> 6;
    const int lr = lane & 15, hi = lane >> 4;
    const int b = hi & 1, g = hi >> 1;
    const bool have2 = (wv < 3);          // waves 0-2: 32 q; wave 3: 16 q
    const int qbase = q0 + wv * 32;

    const int t0 = (s == 0) ? 0 : (17 + 16 * (s - 1));
    const int t1 = t0 + ((s == 0) ? 17 : 16);

    __shared__ char smem[32768];
    char* Ks = smem;            // 64 rows * 256B (k-major, c contiguous), swizzled
    char* Vt = smem + 16384;    // 128 rows * 128B (c-major, v contiguous), swizzled

    const __hip_bfloat16* Kg = Kt + (size_t)n * HW * CH;
    const __hip_bfloat16* Vp = Vg + (size_t)n * CH * HW;

    // Q fragments directly from global (linear [q][c] layout, once per block)
    const __hip_bfloat16* Qg = Qt + ((size_t)n * HW + qbase) * CH;
    const int r1off = have2 ? 16 + lr : lr;   // wave 3: avoid OOB, dup qt0
    bf16x8 qf0[4], qf1[4];
#pragma unroll
    for (int cs = 0; cs < 4; ++cs) {
        qf0[cs] = *(const bf16x8*)(Qg + (size_t)lr * CH + cs * 32 + hi * 8);
        qf1[cs] = *(const bf16x8*)(Qg + (size_t)r1off * CH + cs * 32 + hi * 8);
    }

    // staging geometry (256 threads: K 64x256B, V 128x128B)
    const int krow_s = tid >> 4, kcol_s = tid & 15;
    const int vrow_s = tid >> 3, vcol_s = tid & 7;
    const int kswz = (kcol_s * 16) ^ ((krow_s & 7) << 4);
    const int vswz = (vcol_s * 16) ^ ((vrow_s & 7) << 4);

    bf16x8 kreg[4], vreg[4];
    {
        const int k0 = t0 * 64;
#pragma unroll
        for (int it = 0; it < 4; ++it)
            kreg[it] = *(const bf16x8*)(Kg + (size_t)(k0 + it * 16 + krow_s) * CH + kcol_s * 8);
#pragma unroll
        for (int it = 0; it < 4; ++it)
            vreg[it] = *(const bf16x8*)(Vp + (size_t)(it * 32 + vrow_s) * HW + k0 + vcol_s * 8);
    }
#pragma unroll
    for (int it = 0; it < 4; ++it)
        *(bf16x8*)(Ks + (it * 16 + krow_s) * 256 + kswz) = kreg[it];
#pragma unroll
    for (int it = 0; it < 4; ++it)
        *(bf16x8*)(Vt + (it * 32 + vrow_s) * 128 + vswz) = vreg[it];
    __syncthreads();

    f32x4 O0[8] = {}, O1[8] = {};          // O^T: rows c=cn*16+hi*4+reg, col q=lr
    float m0 = -1e30f, l0 = 0.f;           // state for q = qbase + lr
    float m1 = -1e30f, l1 = 0.f;           // state for q = qbase + 16 + lr

    for (int t = t0; t < t1; ++t) {
        // prefetch next tile into registers
        if (t + 1 < t1) {
            const int k0n = (t + 1) * 64;
#pragma unroll
            for (int it = 0; it < 4; ++it)
                kreg[it] = *(const bf16x8*)(Kg + (size_t)(k0n + it * 16 + krow_s) * CH + kcol_s * 8);
#pragma unroll
            for (int it = 0; it < 4; ++it)
                vreg[it] = *(const bf16x8*)(Vp + (size_t)(it * 32 + vrow_s) * HW + k0n + vcol_s * 8);
        }

        // S^T = K Q^T for both q-subtiles; each kf read feeds 2 MFMAs
        f32x4 s0[4] = {}, s1[4] = {};
#pragma unroll
        for (int kt = 0; kt < 4; ++kt) {
            int krow = kt * 16 + lr;
#pragma unroll
            for (int cs = 0; cs < 4; ++cs) {
                bf16x8 kf = *(const bf16x8*)(Ks + krow * 256 +
                                             ((cs * 64 + hi * 16) ^ ((lr & 7) << 4)));
                s0[kt] = MFMA16(kf, qf0[cs], s0[kt]);
                s1[kt] = MFMA16(kf, qf1[cs], s1[kt]);
            }
        }

        // online softmax qt0
        unsigned pk0[4][2], pk1[4][2];
        {
            float pmax = s0[0][0];
#pragma unroll
            for (int kt = 0; kt < 4; ++kt)
#pragma unroll
                for (int reg = 0; reg < 4; ++reg) pmax = fmaxf(pmax, s0[kt][reg]);
            pmax = fmaxf(pmax, __shfl_xor(pmax, 16));
            pmax = fmaxf(pmax, __shfl_xor(pmax, 32));
            if (__any(pmax > m0)) {
                float nm = fmaxf(m0, pmax);
                float f  = __expf((m0 - nm) * SCALE);
                l0 *= f; m0 = nm;
#pragma unroll
                for (int cn = 0; cn < 8; ++cn) O0[cn] *= f;
            }
            float pp[4][4]; float rs = 0.f;
#pragma unroll
            for (int kt = 0; kt < 4; ++kt)
#pragma unroll
                for (int reg = 0; reg < 4; ++reg) {
                    pp[kt][reg] = __expf((s0[kt][reg] - m0) * SCALE);
                    rs += pp[kt][reg];
                }
            rs += __shfl_xor(rs, 16);
            rs += __shfl_xor(rs, 32);
            l0 += rs;
#pragma unroll
            for (int kt = 0; kt < 4; ++kt) {
                pk0[kt][0] = pack2bf(pp[kt][0], pp[kt][1]);
                pk0[kt][1] = pack2bf(pp[kt][2], pp[kt][3]);
            }
        }
        // online softmax qt1
        {
            float pmax = s1[0][0];
#pragma unroll
            for (int kt = 0; kt < 4; ++kt)
#pragma unroll
                for (int reg = 0; reg < 4; ++reg) pmax = fmaxf(pmax, s1[kt][reg]);
            pmax = fmaxf(pmax, __shfl_xor(pmax, 16));
            pmax = fmaxf(pmax, __shfl_xor(pmax, 32));
            if (__any(pmax > m1)) {
                float nm = fmaxf(m1, pmax);
                float f  = __expf((m1 - nm) * SCALE);
                l1 *= f; m1 = nm;
#pragma unroll
                for (int cn = 0; cn < 8; ++cn) O1[cn] *= f;
            }
            float pp[4][4]; float rs = 0.f;
#pragma unroll
            for (int kt = 0; kt < 4; ++kt)
#pragma unroll
                for (int reg = 0; reg < 4; ++reg) {
                    pp[kt][reg] = __expf((s1[kt][reg] - m1) * SCALE);
                    rs += pp[kt][reg];
                }
            rs += __shfl_xor(rs, 16);
            rs += __shfl_xor(rs, 32);
            l1 += rs;
#pragma unroll
            for (int kt = 0; kt < 4; ++kt) {
                pk1[kt][0] = pack2bf(pp[kt][0], pp[kt][1]);
                pk1[kt][1] = pack2bf(pp[kt][2], pp[kt][3]);
            }
        }

        // O^T += V^T P^T ; each vb read feeds 2 MFMAs
#pragma unroll
        for (int ks = 0; ks < 2; ++ks) {
            union { unsigned u[4]; bf16x8 v; } pf0, pf1;
#pragma unroll
            for (int h = 0; h < 2; ++h) {
                unsigned send1 = b ? pk0[2 * ks + 1][h] : pk0[2 * ks][h];
                unsigned send2 = b ? pk0[2 * ks][h]     : pk0[2 * ks + 1][h];
                unsigned r1 = __shfl((int)send1, (2 * b + g) * 16 + lr);
                unsigned r2 = __shfl((int)send2, (2 * b + (g ^ 1)) * 16 + lr);
                pf0.u[h]     = g ? r2 : r1;
                pf0.u[h + 2] = g ? r1 : r2;
            }
#pragma unroll
            for (int h = 0; h < 2; ++h) {
                unsigned send1 = b ? pk1[2 * ks + 1][h] : pk1[2 * ks][h];
                unsigned send2 = b ? pk1[2 * ks][h]     : pk1[2 * ks + 1][h];
                unsigned r1 = __shfl((int)send1, (2 * b + g) * 16 + lr);
                unsigned r2 = __shfl((int)send2, (2 * b + (g ^ 1)) * 16 + lr);
                pf1.u[h]     = g ? r2 : r1;
                pf1.u[h + 2] = g ? r1 : r2;
            }
#pragma unroll
            for (int cn = 0; cn < 8; ++cn) {
                int vr = cn * 16 + lr;
                bf16x8 vb = *(const bf16x8*)(Vt + vr * 128 +
                                             ((ks * 64 + hi * 16) ^ ((lr & 7) << 4)));
                O0[cn] = MFMA16(vb, pf0.v, O0[cn]);
                O1[cn] = MFMA16(vb, pf1.v, O1[cn]);
            }
        }

        __syncthreads();              // all waves done reading Ks/Vt
        if (t + 1 < t1) {
#pragma unroll
            for (int it = 0; it < 4; ++it)
                *(bf16x8*)(Ks + (it * 16 + krow_s) * 256 + kswz) = kreg[it];
#pragma unroll
            for (int it = 0; it < 4; ++it)
                *(bf16x8*)(Vt + (it * 32 + vrow_s) * 128 + vswz) = vreg[it];
        }
        __syncthreads();
    }

    // stage unnormalized O~ as bf16 [q_local][c] (112 rows x 256B; wave3's
    // phantom qt1 rows 112-127 land in scratch area of smem, never written out)
#pragma unroll
    for (int cn = 0; cn < 8; ++cn) {
        int row = wv * 32 + lr;
        int colb = cn * 32 + hi * 8;
        *(unsigned*)(smem + row * 256 + ((colb)     ^ ((row & 7) << 4))) = pack2bf(O0[cn][0], O0[cn][1]);
        *(unsigned*)(smem + row * 256 + ((colb + 4) ^ ((row & 7) << 4))) = pack2bf(O0[cn][2], O0[cn][3]);
        int row1 = row + 16;
        *(unsigned*)(smem + row1 * 256 + ((colb)     ^ ((row1 & 7) << 4))) = pack2bf(O1[cn][0], O1[cn][1]);
        *(unsigned*)(smem + row1 * 256 + ((colb + 4) ^ ((row1 & 7) << 4))) = pack2bf(O1[cn][2], O1[cn][3]);
    }
    __syncthreads();
    __hip_bfloat16* pg = PO + ((size_t)(s * NB + n) * HW + q0) * CH;
#pragma unroll
    for (int it = 0; it < 7; ++it) {          // 112 rows x 16 chunks / 256 thr
        int ch = it * 256 + tid, r = ch >> 4, o = ch & 15;
        bf16x8 v = *(const bf16x8*)(smem + r * 256 + ((o * 16) ^ ((r & 7) << 4)));
        *(bf16x8*)(pg + (size_t)r * CH + o * 8) = v;
    }
    if (hi == 0) {
        size_t base = (size_t)(s * NB + n) * HW + q0 + wv * 32 + lr;
        Mbuf[base] = m0; Lbuf[base] = l0;
        if (have2) { Mbuf[base + 16] = m1; Lbuf[base + 16] = l1; }
    }
}

// ---------------------------------------------------------------------------
// Kernel 2b: merge KV-split partials -> att bf16 [n][q][c].
// ---------------------------------------------------------------------------
__global__ __launch_bounds__(256) void merge_kernel(
        const __hip_bfloat16* __restrict__ PO,
        const float* __restrict__ Mbuf,
        const float* __restrict__ Lbuf,
        __hip_bfloat16* __restrict__ att) {
    const int idx = blockIdx.x * 256 + threadIdx.x;   // < NB*HW*16
    const int nq = idx >> 4;
    const int c0 = (idx & 15) * 8;
    const size_t NHW = (size_t)NB * HW;
    float m0 = Mbuf[nq], m1 = Mbuf[NHW + nq], m2 = Mbuf[2 * NHW + nq];
    float l0 = Lbuf[nq], l1 = Lbuf[NHW + nq], l2 = Lbuf[2 * NHW + nq];
    float M = fmaxf(m0, fmaxf(m1, m2));
    float w0 = __expf((m0 - M) * SCALE);
    float w1 = __expf((m1 - M) * SCALE);
    float w2 = __expf((m2 - M) * SCALE);
    float rinv = 1.f / (w0 * l0 + w1 * l1 + w2 * l2);
    union { bf16x8 v; unsigned short u[8]; } p0, p1, p2, ov;
    p0.v = *(const bf16x8*)(PO + (size_t)nq * CH + c0);
    p1.v = *(const bf16x8*)(PO + NHW * CH + (size_t)nq * CH + c0);
    p2.v = *(const bf16x8*)(PO + 2 * NHW * CH + (size_t)nq * CH + c0);
#pragma unroll
    for (int j = 0; j < 8; ++j) {
        float a = w0 * bfraw2f(p0.u[j]) + w1 * bfraw2f(p1.u[j]) + w2 * bfraw2f(p2.u[j]);
        ov.u[j] = (unsigned short)f2bf(a * rinv);
    }
    *(bf16x8*)(att + (size_t)nq * CH + c0) = ov.v;
}

// ---------------------------------------------------------------------------
// Kernel 3: z = ZwB @ att[n] via MFMA (K=128), BN + residual. Unchanged.
// ---------------------------------------------------------------------------
__global__ __launch_bounds__(256) void zbn_kernel(const __hip_bfloat16* __restrict__ att,
                                                  const __hip_bfloat16* __restrict__ ZwB,
                                                  const float* __restrict__ gamma,
                                                  const float* __restrict__ beta,
                                                  const float* __restrict__ mean,
                                                  const float* __restrict__ var,
                                                  const float* __restrict__ x,
                                                  float* __restrict__ out) {
    const int n  = blockIdx.z;
    const int m0 = blockIdx.y * 64;   // over 512
    const int q0 = blockIdx.x * 64;   // over 3136
    const int tid = threadIdx.x;
    const int lane = tid & 63, wv = tid >> 6;
    const int lr = lane & 15, hi = lane >> 4;

    __shared__ char smem[32768];
    char* Az = smem;            // [m][128 c] bf16, 64 rows * 256B, swizzled
    char* Ba = smem + 16384;    // [q][128 c] bf16

#pragma unroll
    for (int it = 0; it < 4; ++it) {
        int ch = it * 256 + tid, r = ch >> 4, o = ch & 15;
        int sw = (o * 16) ^ ((r & 7) << 4);
        bf16x8 a = *(const bf16x8*)(ZwB + (size_t)(m0 + r) * CH + o * 8);
        *(bf16x8*)(Az + r * 256 + sw) = a;
        bf16x8 b = *(const bf16x8*)(att + ((size_t)n * HW + q0 + r) * CH + o * 8);
        *(bf16x8*)(Ba + r * 256 + sw) = b;
    }
    __syncthreads();

    f32x4 acc[4] = {};
    const int mrow = wv * 16 + lr;
#pragma unroll
    for (int ks = 0; ks < 4; ++ks) {
        bf16x8 af = *(const bf16x8*)(Az + mrow * 256 +
                                     ((ks * 64 + hi * 16) ^ ((mrow & 7) << 4)));
#pragma unroll
        for (int kn = 0; kn < 4; ++kn) {
            int qrow = kn * 16 + lr;
            bf16x8 bfr = *(const bf16x8*)(Ba + qrow * 256 +
                                          ((ks * 64 + hi * 16) ^ ((qrow & 7) << 4)));
            acc[kn] = MFMA16(af, bfr, acc[kn]);
        }
    }
    __syncthreads();   // smem reused for epilogue staging

    float inv[4], add[4];
#pragma unroll
    for (int reg = 0; reg < 4; ++reg) {
        int m = m0 + wv * 16 + hi * 4 + reg;
        inv[reg] = gamma[m] * rsqrtf(var[m] + BNEPS);
        add[reg] = beta[m] - mean[m] * inv[reg];
    }

#pragma unroll
    for (int kn = 0; kn < 4; ++kn)
#pragma unroll
        for (int reg = 0; reg < 4; ++reg) {
            int row = wv * 16 + hi * 4 + reg;
            int colb = (kn * 16 + lr) * 4;
            *(float*)(smem + row * 256 + (colb ^ ((row & 7) << 4))) =
                acc[kn][reg] * inv[reg] + add[reg];
        }
    __syncthreads();

#pragma unroll
    for (int it = 0; it < 4; ++it) {
        int ch = it * 256 + tid, rr = ch >> 4, o = ch & 15;
        f32x4 v = *(const f32x4*)(smem + rr * 256 + ((o * 16) ^ ((rr & 7) << 4)));
        size_t idx = (size_t)n * CIN * HW + (size_t)(m0 + rr) * HW + q0 + o * 4;
        float4 xv = *(const float4*)(x + idx);
        float4 ov; ov.x = v[0] + xv.x; ov.y = v[1] + xv.y;
                   ov.z = v[2] + xv.z; ov.w = v[3] + xv.w;
        *(float4*)(out + idx) = ov;
    }
}

// ---------------------------------------------------------------------------
extern "C" void kernel_launch(void* const* d_in, const int* in_sizes, int n_in,
                              void* d_out, int out_size, void* d_ws, size_t ws_size,
                              hipStream_t stream) {
    const float* x     = (const float*)d_in[0];
    const float* Ww    = (const float*)d_in[1];
    const float* Wb    = (const float*)d_in[2];
    const float* Zw    = (const float*)d_in[3];
    const float* gamma = (const float*)d_in[4];
    const float* beta  = (const float*)d_in[5];
    const float* mean  = (const float*)d_in[6];
    const float* var   = (const float*)d_in[7];
    float* out = (float*)d_out;

    // d_out scratch chain (51.38 MB total), all dead before zbn writes out:
    //   [0, 25.69M)   xT        (xpose -> proj)
    //   [25.69, 45.0M) Qt/Kt/Vg (proj -> attn)
    //   [0, 19.27M)   PO partials (attn -> merge; overlays dead xT)
    const size_t xT_bytes  = (size_t)NB * HW * CIN * 2;   // 25,690,112
    const size_t qkv_bytes = (size_t)NB * HW * CH * 2;    //  6,422,528 each
    char* ob = (char*)d_out;
    __hip_bfloat16* xT  = (__hip_bfloat16*)ob;
    __hip_bfloat16* Qt  = (__hip_bfloat16*)(ob + xT_bytes);
    __hip_bfloat16* Kt  = (__hip_bfloat16*)(ob + xT_bytes + qkv_bytes);
    __hip_bfloat16* Vgb = (__hip_bfloat16*)(ob + xT_bytes + 2 * qkv_bytes);
    __hip_bfloat16* PO  = (__hip_bfloat16*)ob;

    // workspace: attb + weights + m/l  (~7.5 MB; ws proven >= 12.85 MB)
    char* w = (char*)d_ws;
    __hip_bfloat16* attb = (__hip_bfloat16*)w;                       w += qkv_bytes;
    __hip_bfloat16* WwB  = (__hip_bfloat16*)w;                       w += (size_t)TCH * CIN * 2;
    __hip_bfloat16* ZwB  = (__hip_bfloat16*)w;                       w += (size_t)CIN * CH * 2;
    float* Mbuf = (float*)w;                                         w += (size_t)NSPLIT * NB * HW * 4;
    float* Lbuf = (float*)w;

    cvt_wts<<<dim3(256), 256, 0, stream>>>(Ww, Zw, WwB, ZwB);
    xpose_kernel<<<dim3(HW / 64, CIN / 64, NB), 256, 0, stream>>>(x, xT);
    proj_kernel<<<dim3(HW / 64, TCH / 64, NB), 256, 0, stream>>>(xT, WwB, Wb, Qt, Kt, Vgb);
    attn_kernel<<<dim3(HW / 112, NB, NSPLIT), 256, 0, stream>>>(Qt, Kt, Vgb, PO, Mbuf, Lbuf);
    merge_kernel<<<dim3(NB * HW * 16 / 256), 256, 0, stream>>>(PO, Mbuf, Lbuf, attb);
    zbn_kernel<<<dim3(HW / 64, CIN / 64, NB), 256, 0, stream>>>(attb, ZwB, gamma, beta,
                                                                mean, var, x, out);
}

// Round 6
// 163.445 us; speedup vs baseline: 1.2946x; 1.2946x over previous
//
#include <hip/hip_runtime.h>
#include <hip/hip_bf16.h>
#include <math.h>

// Problem constants
#define NB    8          // batch
#define CIN   512        // in channels
#define HW    3136       // 56*56
#define CH    128        // attention channels
#define TCH   384        // 3*CH
#define SCALE 0.08838834764831845f   // 128^-0.5
#define BNEPS 1e-5f
#define NSPLIT 4         // KV splits for attention (tiles 13/12/12/12 of 49)

typedef __attribute__((ext_vector_type(8))) short bf16x8;   // 8 bf16 (4 VGPRs)
typedef __attribute__((ext_vector_type(4))) short bf16x4;   // 4 bf16 (2 VGPRs)
typedef __attribute__((ext_vector_type(4))) float f32x4;    // MFMA accumulator

#define MFMA16(a, b, c) __builtin_amdgcn_mfma_f32_16x16x32_bf16((a), (b), (c), 0, 0, 0)

__device__ inline short f2bf(float f) {
    __hip_bfloat16 h = __float2bfloat16(f);
    return *reinterpret_cast<short*>(&h);
}
__device__ inline unsigned pack2bf(float a, float b) {
    return (unsigned)(unsigned short)f2bf(a) | ((unsigned)(unsigned short)f2bf(b) << 16);
}
__device__ inline float bfraw2f(unsigned short u) {
    return __uint_as_float(((unsigned)u) << 16);
}

// ---------------------------------------------------------------------------
// Kernel 0a: convert Ww (384x512) and Zw (512x128) f32 -> bf16, row-major.
// ---------------------------------------------------------------------------
__global__ __launch_bounds__(256) void cvt_wts(const float* __restrict__ Ww,
                                               const float* __restrict__ Zw,
                                               __hip_bfloat16* __restrict__ WwB,
                                               __hip_bfloat16* __restrict__ ZwB) {
    const int nW = TCH * CIN / 4;   // 49152 float4 chunks
    const int nZ = CIN * CH / 4;    // 16384
    int i = blockIdx.x * 256 + threadIdx.x;
    if (i < nW) {
        float4 v = ((const float4*)Ww)[i];
        bf16x4 o; o[0] = f2bf(v.x); o[1] = f2bf(v.y); o[2] = f2bf(v.z); o[3] = f2bf(v.w);
        ((bf16x4*)WwB)[i] = o;
    } else if (i < nW + nZ) {
        int j = i - nW;
        float4 v = ((const float4*)Zw)[j];
        bf16x4 o; o[0] = f2bf(v.x); o[1] = f2bf(v.y); o[2] = f2bf(v.z); o[3] = f2bf(v.w);
        ((bf16x4*)ZwB)[j] = o;
    }
}

// ---------------------------------------------------------------------------
// Kernel 0b: xT[n][q][c] bf16 = transpose+cvt of x[n][c][q] f32.
// ---------------------------------------------------------------------------
__global__ __launch_bounds__(256) void xpose_kernel(const float* __restrict__ x,
                                                    __hip_bfloat16* __restrict__ xT) {
    const int n = blockIdx.z, c0 = blockIdx.y * 64, q0 = blockIdx.x * 64;
    const int tid = threadIdx.x;
    const int mr = tid >> 4, mq = tid & 15;

    __shared__ char T[64 * 128];   // [q][64 c] bf16, byte ^= ((q&15)<<3)

    const float* xp = x + ((size_t)(n * CIN + c0 + mr * 4)) * HW + q0 + mq * 4;
    float4 r0 = *(const float4*)(xp);
    float4 r1 = *(const float4*)(xp + HW);
    float4 r2 = *(const float4*)(xp + 2 * HW);
    float4 r3 = *(const float4*)(xp + 3 * HW);
    const float* f0 = (const float*)&r0; const float* f1 = (const float*)&r1;
    const float* f2 = (const float*)&r2; const float* f3 = (const float*)&r3;
#pragma unroll
    for (int j = 0; j < 4; ++j) {
        int q = mq * 4 + j;
        bf16x4 v; v[0] = f2bf(f0[j]); v[1] = f2bf(f1[j]);
                  v[2] = f2bf(f2[j]); v[3] = f2bf(f3[j]);
        *(bf16x4*)(T + q * 128 + ((mr * 8) ^ ((q & 15) << 3))) = v;
    }
    __syncthreads();

    __hip_bfloat16* og = xT + ((size_t)n * HW + q0) * CIN + c0;
#pragma unroll
    for (int it = 0; it < 2; ++it) {
        int ch = it * 256 + tid, rr = ch >> 3, o8 = ch & 7;
        int sw = (rr & 15) << 3;
        bf16x4 lo = *(const bf16x4*)(T + rr * 128 + ((o8 * 16) ^ sw));
        bf16x4 hi = *(const bf16x4*)(T + rr * 128 + ((o8 * 16 + 8) ^ sw));
        bf16x8 v; v[0] = lo[0]; v[1] = lo[1]; v[2] = lo[2]; v[3] = lo[3];
                  v[4] = hi[0]; v[5] = hi[1]; v[6] = hi[2]; v[7] = hi[3];
        *(bf16x8*)(og + (size_t)rr * CIN + o8 * 8) = v;
    }
}

// ---------------------------------------------------------------------------
// Kernel 1: proj via MFMA (unchanged).
// ---------------------------------------------------------------------------
__global__ __launch_bounds__(256) void proj_kernel(const __hip_bfloat16* __restrict__ xT,
                                                   const __hip_bfloat16* __restrict__ WwB,
                                                   const float* __restrict__ Wb,
                                                   __hip_bfloat16* __restrict__ Qt,
                                                   __hip_bfloat16* __restrict__ Kt,
                                                   __hip_bfloat16* __restrict__ Vg) {
    const int n  = blockIdx.z;
    const int m0 = blockIdx.y * 64;   // over 384
    const int q0 = blockIdx.x * 64;   // over 3136
    const int tid = threadIdx.x;
    const int lane = tid & 63, wv = tid >> 6;
    const int lr = lane & 15, hi = lane >> 4;

    __shared__ char Aw[64 * 128];  // [m][64 c] bf16, byte ^= ((r&7)<<4)
    __shared__ char Bx[64 * 128];  // [q][64 c]
    __shared__ char Ts[64 * 128];  // epilogue staging

    f32x4 acc[4] = {};
    const __hip_bfloat16* xn = xT + ((size_t)n * HW + q0) * CIN;

    for (int k0 = 0; k0 < CIN; k0 += 64) {
#pragma unroll
        for (int it = 0; it < 2; ++it) {
            int ch = it * 256 + tid, r = ch >> 3, o = ch & 7;
            int sw = (o * 16) ^ ((r & 7) << 4);
            bf16x8 a = *(const bf16x8*)(WwB + (size_t)(m0 + r) * CIN + k0 + o * 8);
            *(bf16x8*)(Aw + r * 128 + sw) = a;
            bf16x8 b = *(const bf16x8*)(xn + (size_t)r * CIN + k0 + o * 8);
            *(bf16x8*)(Bx + r * 128 + sw) = b;
        }
        __syncthreads();

        const int mrow = wv * 16 + lr;
#pragma unroll
        for (int ks = 0; ks < 2; ++ks) {
            bf16x8 af = *(const bf16x8*)(Aw + mrow * 128 +
                                         ((ks * 64 + hi * 16) ^ ((mrow & 7) << 4)));
#pragma unroll
            for (int kn = 0; kn < 4; ++kn) {
                int qrow = kn * 16 + lr;
                bf16x8 bfr = *(const bf16x8*)(Bx + qrow * 128 +
                                              ((ks * 64 + hi * 16) ^ ((qrow & 7) << 4)));
                acc[kn] = MFMA16(af, bfr, acc[kn]);
            }
        }
        __syncthreads();
    }

    const int region = m0 >> 7;     // 0=Q, 1=K, 2=V
    const int c0     = m0 & 127;    // 0 or 64

    float bias[4];
#pragma unroll
    for (int reg = 0; reg < 4; ++reg) bias[reg] = Wb[m0 + wv * 16 + hi * 4 + reg];

#pragma unroll
    for (int kn = 0; kn < 4; ++kn)
#pragma unroll
        for (int reg = 0; reg < 4; ++reg) {
            __hip_bfloat16 v = __float2bfloat16(acc[kn][reg] + bias[reg]);
            int row, colb;
            if (region < 2) { row = kn * 16 + lr; colb = (wv * 16 + hi * 4 + reg) * 2; }
            else            { row = wv * 16 + hi * 4 + reg; colb = (kn * 16 + lr) * 2; }
            *(__hip_bfloat16*)(Ts + row * 128 + (colb ^ ((row & 7) << 4))) = v;
        }
    __syncthreads();

    __hip_bfloat16* base;
    size_t rstride;
    if (region == 0)      { base = Qt + (size_t)n * HW * CH + (size_t)q0 * CH + c0; rstride = CH; }
    else if (region == 1) { base = Kt + (size_t)n * HW * CH + (size_t)q0 * CH + c0; rstride = CH; }
    else                  { base = Vg + (size_t)n * CH * HW + (size_t)c0 * HW + q0; rstride = HW; }

#pragma unroll
    for (int it = 0; it < 2; ++it) {
        int ch = it * 256 + tid, rr = ch >> 3, o = ch & 7;
        bf16x8 v = *(const bf16x8*)(Ts + rr * 128 + ((o * 16) ^ ((rr & 7) << 4)));
        *(bf16x8*)(base + (size_t)rr * rstride + o * 8) = v;
    }
}

// ---------------------------------------------------------------------------
// Kernel 2: flash attention, R4 structure (Nq=16/wave, 64 VGPR) + KV-split 4.
// Writes unnormalized bf16 partial O~ + f32 m,l per (split, q).
// ---------------------------------------------------------------------------
__global__ __launch_bounds__(256) void attn_kernel(
        const __hip_bfloat16* __restrict__ Qt,   // [NB][HW][CH]
        const __hip_bfloat16* __restrict__ Kt,   // [NB][HW][CH]
        const __hip_bfloat16* __restrict__ Vg,   // [NB][CH][HW]
        __hip_bfloat16* __restrict__ PO,         // [NSPLIT][NB][HW][CH]
        float* __restrict__ Mbuf,                // [NSPLIT][NB][HW]
        float* __restrict__ Lbuf) {              // [NSPLIT][NB][HW]
    const int n = blockIdx.y, s = blockIdx.z;
    const int q0 = blockIdx.x * 64;
    const int tid = threadIdx.x, lane = tid & 63, wv = tid >> 6;
    const int lr = lane & 15, hi = lane >> 4;
    const int b = hi & 1, g = hi >> 1;

    const int t0 = (s == 0) ? 0 : (13 + 12 * (s - 1));
    const int t1 = t0 + ((s == 0) ? 13 : 12);

    __shared__ char smem[32768];
    char* Ks = smem;            // 64 rows * 256B (k-major, c contiguous), swizzled
    char* Vt = smem + 16384;    // 128 rows * 128B (c-major, v contiguous), swizzled

    const __hip_bfloat16* Kg = Kt + (size_t)n * HW * CH;
    const __hip_bfloat16* Vp = Vg + (size_t)n * CH * HW;

    // Q fragments directly from global ([q][c] c-contiguous); wave owns 16 q
    const __hip_bfloat16* Qg = Qt + ((size_t)n * HW + q0 + wv * 16) * CH;
    bf16x8 qf[4];
#pragma unroll
    for (int cs = 0; cs < 4; ++cs)
        qf[cs] = *(const bf16x8*)(Qg + (size_t)lr * CH + cs * 32 + hi * 8);

    // staging geometry (256 threads: K 64x256B, V 128x128B)
    const int krow_s = tid >> 4, kcol_s = tid & 15;
    const int vrow_s = tid >> 3, vcol_s = tid & 7;
    const int kswz = (kcol_s * 16) ^ ((krow_s & 7) << 4);
    const int vswz = (vcol_s * 16) ^ ((vrow_s & 7) << 4);

    bf16x8 kreg[4], vreg[4];
    {
        const int k0 = t0 * 64;
#pragma unroll
        for (int it = 0; it < 4; ++it)
            kreg[it] = *(const bf16x8*)(Kg + (size_t)(k0 + it * 16 + krow_s) * CH + kcol_s * 8);
#pragma unroll
        for (int it = 0; it < 4; ++it)
            vreg[it] = *(const bf16x8*)(Vp + (size_t)(it * 32 + vrow_s) * HW + k0 + vcol_s * 8);
    }
#pragma unroll
    for (int it = 0; it < 4; ++it)
        *(bf16x8*)(Ks + (it * 16 + krow_s) * 256 + kswz) = kreg[it];
#pragma unroll
    for (int it = 0; it < 4; ++it)
        *(bf16x8*)(Vt + (it * 32 + vrow_s) * 128 + vswz) = vreg[it];
    __syncthreads();

    f32x4 O[8] = {};                  // O^T: rows c=cn*16+hi*4+reg, col q=lr
    float m_i = -1e30f, l_i = 0.f;    // per-lane state for q = q0 + wv*16 + lr

    for (int t = t0; t < t1; ++t) {
        // prefetch next tile into registers
        if (t + 1 < t1) {
            const int k0n = (t + 1) * 64;
#pragma unroll
            for (int it = 0; it < 4; ++it)
                kreg[it] = *(const bf16x8*)(Kg + (size_t)(k0n + it * 16 + krow_s) * CH + kcol_s * 8);
#pragma unroll
            for (int it = 0; it < 4; ++it)
                vreg[it] = *(const bf16x8*)(Vp + (size_t)(it * 32 + vrow_s) * HW + k0n + vcol_s * 8);
        }

        // S^T = K Q^T : sacc[kt] rows k=kt*16.., cols q (wave's 16 q)
        f32x4 sacc[4] = {};
#pragma unroll
        for (int kt = 0; kt < 4; ++kt) {
            int krow = kt * 16 + lr;
#pragma unroll
            for (int cs = 0; cs < 4; ++cs) {
                bf16x8 kf = *(const bf16x8*)(Ks + krow * 256 +
                                             ((cs * 64 + hi * 16) ^ ((lr & 7) << 4)));
                sacc[kt] = MFMA16(kf, qf[cs], sacc[kt]);
            }
        }

        // online softmax, all in-lane (q = lr), cross-hi via 2 shuffles
        float pmax = sacc[0][0];
#pragma unroll
        for (int kt = 0; kt < 4; ++kt)
#pragma unroll
            for (int reg = 0; reg < 4; ++reg) pmax = fmaxf(pmax, sacc[kt][reg]);
        pmax = fmaxf(pmax, __shfl_xor(pmax, 16));
        pmax = fmaxf(pmax, __shfl_xor(pmax, 32));

        if (__any(pmax > m_i)) {
            float nm = fmaxf(m_i, pmax);
            float f  = __expf((m_i - nm) * SCALE);
            l_i *= f; m_i = nm;
#pragma unroll
            for (int cn = 0; cn < 8; ++cn) O[cn] *= f;
        }

        float pp[4][4];
        float rs = 0.f;
#pragma unroll
        for (int kt = 0; kt < 4; ++kt)
#pragma unroll
            for (int reg = 0; reg < 4; ++reg) {
                pp[kt][reg] = __expf((sacc[kt][reg] - m_i) * SCALE);
                rs += pp[kt][reg];
            }
        rs += __shfl_xor(rs, 16);
        rs += __shfl_xor(rs, 32);
        l_i += rs;

        // pack P to bf16 pairs: pk[kt][h] covers k = kt*16+hi*4+{2h,2h+1}
        unsigned pk[4][2];
#pragma unroll
        for (int kt = 0; kt < 4; ++kt) {
            pk[kt][0] = pack2bf(pp[kt][0], pp[kt][1]);
            pk[kt][1] = pack2bf(pp[kt][2], pp[kt][3]);
        }

        // O^T += V^T P^T ; P-frags assembled in-register via 8 shuffles
#pragma unroll
        for (int ks = 0; ks < 2; ++ks) {
            union { unsigned u[4]; bf16x8 v; } pf;
#pragma unroll
            for (int h = 0; h < 2; ++h) {
                unsigned send1 = b ? pk[2 * ks + 1][h] : pk[2 * ks][h];
                unsigned send2 = b ? pk[2 * ks][h]     : pk[2 * ks + 1][h];
                unsigned r1 = __shfl((int)send1, (2 * b + g) * 16 + lr);
                unsigned r2 = __shfl((int)send2, (2 * b + (g ^ 1)) * 16 + lr);
                pf.u[h]     = g ? r2 : r1;
                pf.u[h + 2] = g ? r1 : r2;
            }
#pragma unroll
            for (int cn = 0; cn < 8; ++cn) {
                int vr = cn * 16 + lr;
                bf16x8 vb = *(const bf16x8*)(Vt + vr * 128 +
                                             ((ks * 64 + hi * 16) ^ ((lr & 7) << 4)));
                O[cn] = MFMA16(vb, pf.v, O[cn]);
            }
        }

        __syncthreads();              // all waves done reading Ks/Vt
        if (t + 1 < t1) {
#pragma unroll
            for (int it = 0; it < 4; ++it)
                *(bf16x8*)(Ks + (it * 16 + krow_s) * 256 + kswz) = kreg[it];
#pragma unroll
            for (int it = 0; it < 4; ++it)
                *(bf16x8*)(Vt + (it * 32 + vrow_s) * 128 + vswz) = vreg[it];
        }
        __syncthreads();
    }

    // stage unnormalized O~ as bf16 [q_local][c] through LDS, write partials
    const int row = wv * 16 + lr;
#pragma unroll
    for (int cn = 0; cn < 8; ++cn) {
        int colb = cn * 32 + hi * 8;
        *(unsigned*)(smem + row * 256 + ((colb)     ^ ((row & 7) << 4))) = pack2bf(O[cn][0], O[cn][1]);
        *(unsigned*)(smem + row * 256 + ((colb + 4) ^ ((row & 7) << 4))) = pack2bf(O[cn][2], O[cn][3]);
    }
    __syncthreads();
    __hip_bfloat16* pg = PO + ((size_t)(s * NB + n) * HW + q0) * CH;
#pragma unroll
    for (int it = 0; it < 4; ++it) {          // 64 rows x 16 chunks / 256 thr
        int ch = it * 256 + tid, r = ch >> 4, o = ch & 15;
        bf16x8 v = *(const bf16x8*)(smem + r * 256 + ((o * 16) ^ ((r & 7) << 4)));
        *(bf16x8*)(pg + (size_t)r * CH + o * 8) = v;
    }
    if (hi == 0) {
        size_t base = (size_t)(s * NB + n) * HW + q0 + wv * 16 + lr;
        Mbuf[base] = m_i; Lbuf[base] = l_i;
    }
}

// ---------------------------------------------------------------------------
// Kernel 2b: merge KV-split partials -> att bf16 [n][q][c].
// ---------------------------------------------------------------------------
__global__ __launch_bounds__(256) void merge_kernel(
        const __hip_bfloat16* __restrict__ PO,
        const float* __restrict__ Mbuf,
        const float* __restrict__ Lbuf,
        __hip_bfloat16* __restrict__ att) {
    const int idx = blockIdx.x * 256 + threadIdx.x;   // < NB*HW*16
    const int nq = idx >> 4;
    const int c0 = (idx & 15) * 8;
    const size_t NHW = (size_t)NB * HW;

    float m[NSPLIT], l[NSPLIT];
#pragma unroll
    for (int s = 0; s < NSPLIT; ++s) { m[s] = Mbuf[s * NHW + nq]; l[s] = Lbuf[s * NHW + nq]; }
    float M = m[0];
#pragma unroll
    for (int s = 1; s < NSPLIT; ++s) M = fmaxf(M, m[s]);
    float w[NSPLIT], denom = 0.f;
#pragma unroll
    for (int s = 0; s < NSPLIT; ++s) { w[s] = __expf((m[s] - M) * SCALE); denom += w[s] * l[s]; }
    float rinv = 1.f / denom;

    float acc[8] = {};
#pragma unroll
    for (int s = 0; s < NSPLIT; ++s) {
        union { bf16x8 v; unsigned short u[8]; } p;
        p.v = *(const bf16x8*)(PO + (size_t)s * NHW * CH + (size_t)nq * CH + c0);
#pragma unroll
        for (int j = 0; j < 8; ++j) acc[j] += w[s] * bfraw2f(p.u[j]);
    }
    union { bf16x8 v; unsigned short u[8]; } ov;
#pragma unroll
    for (int j = 0; j < 8; ++j) ov.u[j] = (unsigned short)f2bf(acc[j] * rinv);
    *(bf16x8*)(att + (size_t)nq * CH + c0) = ov.v;
}

// ---------------------------------------------------------------------------
// Kernel 3: z = ZwB @ att[n] via MFMA (K=128), BN + residual. Unchanged.
// ---------------------------------------------------------------------------
__global__ __launch_bounds__(256) void zbn_kernel(const __hip_bfloat16* __restrict__ att,
                                                  const __hip_bfloat16* __restrict__ ZwB,
                                                  const float* __restrict__ gamma,
                                                  const float* __restrict__ beta,
                                                  const float* __restrict__ mean,
                                                  const float* __restrict__ var,
                                                  const float* __restrict__ x,
                                                  float* __restrict__ out) {
    const int n  = blockIdx.z;
    const int m0 = blockIdx.y * 64;   // over 512
    const int q0 = blockIdx.x * 64;   // over 3136
    const int tid = threadIdx.x;
    const int lane = tid & 63, wv = tid >> 6;
    const int lr = lane & 15, hi = lane >> 4;

    __shared__ char smem[32768];
    char* Az = smem;            // [m][128 c] bf16, 64 rows * 256B, swizzled
    char* Ba = smem + 16384;    // [q][128 c] bf16

#pragma unroll
    for (int it = 0; it < 4; ++it) {
        int ch = it * 256 + tid, r = ch >> 4, o = ch & 15;
        int sw = (o * 16) ^ ((r & 7) << 4);
        bf16x8 a = *(const bf16x8*)(ZwB + (size_t)(m0 + r) * CH + o * 8);
        *(bf16x8*)(Az + r * 256 + sw) = a;
        bf16x8 b = *(const bf16x8*)(att + ((size_t)n * HW + q0 + r) * CH + o * 8);
        *(bf16x8*)(Ba + r * 256 + sw) = b;
    }
    __syncthreads();

    f32x4 acc[4] = {};
    const int mrow = wv * 16 + lr;
#pragma unroll
    for (int ks = 0; ks < 4; ++ks) {
        bf16x8 af = *(const bf16x8*)(Az + mrow * 256 +
                                     ((ks * 64 + hi * 16) ^ ((mrow & 7) << 4)));
#pragma unroll
        for (int kn = 0; kn < 4; ++kn) {
            int qrow = kn * 16 + lr;
            bf16x8 bfr = *(const bf16x8*)(Ba + qrow * 256 +
                                          ((ks * 64 + hi * 16) ^ ((qrow & 7) << 4)));
            acc[kn] = MFMA16(af, bfr, acc[kn]);
        }
    }
    __syncthreads();   // smem reused for epilogue staging

    float inv[4], add[4];
#pragma unroll
    for (int reg = 0; reg < 4; ++reg) {
        int m = m0 + wv * 16 + hi * 4 + reg;
        inv[reg] = gamma[m] * rsqrtf(var[m] + BNEPS);
        add[reg] = beta[m] - mean[m] * inv[reg];
    }

#pragma unroll
    for (int kn = 0; kn < 4; ++kn)
#pragma unroll
        for (int reg = 0; reg < 4; ++reg) {
            int row = wv * 16 + hi * 4 + reg;
            int colb = (kn * 16 + lr) * 4;
            *(float*)(smem + row * 256 + (colb ^ ((row & 7) << 4))) =
                acc[kn][reg] * inv[reg] + add[reg];
        }
    __syncthreads();

#pragma unroll
    for (int it = 0; it < 4; ++it) {
        int ch = it * 256 + tid, rr = ch >> 4, o = ch & 15;
        f32x4 v = *(const f32x4*)(smem + rr * 256 + ((o * 16) ^ ((rr & 7) << 4)));
        size_t idx = (size_t)n * CIN * HW + (size_t)(m0 + rr) * HW + q0 + o * 4;
        float4 xv = *(const float4*)(x + idx);
        float4 ov; ov.x = v[0] + xv.x; ov.y = v[1] + xv.y;
                   ov.z = v[2] + xv.z; ov.w = v[3] + xv.w;
        *(float4*)(out + idx) = ov;
    }
}

// ---------------------------------------------------------------------------
extern "C" void kernel_launch(void* const* d_in, const int* in_sizes, int n_in,
                              void* d_out, int out_size, void* d_ws, size_t ws_size,
                              hipStream_t stream) {
    const float* x     = (const float*)d_in[0];
    const float* Ww    = (const float*)d_in[1];
    const float* Wb    = (const float*)d_in[2];
    const float* Zw    = (const float*)d_in[3];
    const float* gamma = (const float*)d_in[4];
    const float* beta  = (const float*)d_in[5];
    const float* mean  = (const float*)d_in[6];
    const float* var   = (const float*)d_in[7];
    float* out = (float*)d_out;

    // d_out scratch chain (51.38 MB total), all dead before zbn writes out:
    //   [0, 25.69M)    xT        (xpose -> proj)
    //   [25.69, 45.0M) Qt/Kt/Vg  (proj -> attn)
    //   [0, 25.69M)    PO x4     (attn -> merge; overlays dead xT, exact fit)
    const size_t xT_bytes  = (size_t)NB * HW * CIN * 2;   // 25,690,112
    const size_t qkv_bytes = (size_t)NB * HW * CH * 2;    //  6,422,528 each
    char* ob = (char*)d_out;
    __hip_bfloat16* xT  = (__hip_bfloat16*)ob;
    __hip_bfloat16* Qt  = (__hip_bfloat16*)(ob + xT_bytes);
    __hip_bfloat16* Kt  = (__hip_bfloat16*)(ob + xT_bytes + qkv_bytes);
    __hip_bfloat16* Vgb = (__hip_bfloat16*)(ob + xT_bytes + 2 * qkv_bytes);
    __hip_bfloat16* PO  = (__hip_bfloat16*)ob;            // NSPLIT*qkv = xT_bytes

    // workspace: attb + weights + m/l  (~8 MB; ws proven >= 12.85 MB)
    char* w = (char*)d_ws;
    __hip_bfloat16* attb = (__hip_bfloat16*)w;                       w += qkv_bytes;
    __hip_bfloat16* WwB  = (__hip_bfloat16*)w;                       w += (size_t)TCH * CIN * 2;
    __hip_bfloat16* ZwB  = (__hip_bfloat16*)w;                       w += (size_t)CIN * CH * 2;
    float* Mbuf = (float*)w;                                         w += (size_t)NSPLIT * NB * HW * 4;
    float* Lbuf = (float*)w;

    cvt_wts<<<dim3(256), 256, 0, stream>>>(Ww, Zw, WwB, ZwB);
    xpose_kernel<<<dim3(HW / 64, CIN / 64, NB), 256, 0, stream>>>(x, xT);
    proj_kernel<<<dim3(HW / 64, TCH / 64, NB), 256, 0, stream>>>(xT, WwB, Wb, Qt, Kt, Vgb);
    attn_kernel<<<dim3(HW / 64, NB, NSPLIT), 256, 0, stream>>>(Qt, Kt, Vgb, PO, Mbuf, Lbuf);
    merge_kernel<<<dim3(NB * HW * 16 / 256), 256, 0, stream>>>(PO, Mbuf, Lbuf, attb);
    zbn_kernel<<<dim3(HW / 64, CIN / 64, NB), 256, 0, stream>>>(attb, ZwB, gamma, beta,
                                                                mean, var, x, out);
}